// Round 8
// baseline (695.645 us; speedup 1.0000x reference)
//
#include <hip/hip_runtime.h>

#define NU 4096
#define NI 8192
#define ND 64
#define NTOT 12288
#define CT 8           // top split-K chunks  (K=NU,  ck=512)
#define CB 16          // bottom split-K chunks (K=NI, ck=512)
#define BROW 520       // u16 per staged dense row (512 + 8 pad)
#define NTILE 192      // 128 top + 64 bottom output tiles

typedef unsigned short u16;
typedef unsigned int u32;
typedef unsigned long long u64;

__device__ __forceinline__ u16 f2bf(float f) {
    union { float f; u32 u; } v; v.f = f;
    u32 u = v.u;
    u += 0x7FFFu + ((u >> 16) & 1u);   // round-to-nearest-even
    return (u16)(u >> 16);
}

typedef short frag8 __attribute__((ext_vector_type(8)));
typedef float f32x4 __attribute__((ext_vector_type(4)));

// ---------------------------------------------------------------------------
// K0: edge (int32 0/1) -> bit-packed A AND AT. 512 blocks (2/CU) of
// 128 rows x 512 cols.
// ---------------------------------------------------------------------------
__global__ __launch_bounds__(256) void k_pack2(const int* __restrict__ edge,
        u64* __restrict__ Apk, u64* __restrict__ ATpk) {
    __shared__ __align__(16) u16 At[128][40];   // 10 KB
    __shared__ __align__(16) u64 Tt[512][2];    // 8 KB
    const int t = threadIdx.x;
    const int u0 = (blockIdx.x >> 4) * 128;
    const int i0 = (blockIdx.x & 15) * 512;
    const int cg = t & 31;          // 16-col group
    const int rb = t >> 5;          // row-group (16 rows each)

    #pragma unroll 4
    for (int rr = 0; rr < 16; rr++) {
        const int row = rb * 16 + rr;
        const int4* p = (const int4*)(edge + (size_t)(u0 + row) * NI + i0 + cg * 16);
        u32 bits = 0;
        #pragma unroll
        for (int m = 0; m < 4; m++) {
            int4 v = p[m];
            bits |= (v.x != 0 ? 1u : 0u) << (m * 4 + 0);
            bits |= (v.y != 0 ? 1u : 0u) << (m * 4 + 1);
            bits |= (v.z != 0 ? 1u : 0u) << (m * 4 + 2);
            bits |= (v.w != 0 ? 1u : 0u) << (m * 4 + 3);
        }
        At[row][cg] = (u16)bits;
    }
    __syncthreads();

    {   // Apk store: 32 B per thread (2 x uint4), fully coalesced
        const int row = t >> 1, h = t & 1;
        uint4 v0 = *(const uint4*)&At[row][h * 16];
        uint4 v1 = *(const uint4*)&At[row][h * 16 + 8];
        u64* dst = Apk + (size_t)(u0 + row) * 128 + (i0 >> 6) + h * 4;
        *(uint4*)dst = v0;
        *(uint4*)(dst + 2) = v1;
    }

    {   // 64x64 bit-transpose subtiles (2 row-subtiles x 8 col-subtiles)
        const int lane = t & 63, w = t >> 6;
        const u64 M[6] = {0x00000000FFFFFFFFULL, 0x0000FFFF0000FFFFULL,
                          0x00FF00FF00FF00FFULL, 0x0F0F0F0F0F0F0F0FULL,
                          0x3333333333333333ULL, 0x5555555555555555ULL};
        #pragma unroll
        for (int m = 0; m < 4; m++) {
            const int id = m * 4 + w;
            const int sr = id >> 3, sc = id & 7;
            u64 x = *(const u64*)&At[sr * 64 + lane][sc * 4];
            #pragma unroll
            for (int si = 0; si < 6; si++) {
                const int s = 32 >> si;
                u64 y = __shfl_xor(x, s, 64);
                x = (lane & s) ? ((x & ~M[si]) | ((y >> s) & M[si]))
                               : ((x &  M[si]) | ((y << s) & ~M[si]));
            }
            Tt[sc * 64 + lane][sr] = x;
        }
    }
    __syncthreads();
    #pragma unroll
    for (int j = 0; j < 2; j++) {
        const int item = t * 2 + j;
        ulonglong2 a = *(const ulonglong2*)&Tt[item][0];
        *(ulonglong2*)(ATpk + (size_t)(i0 + item) * 64 + (u0 >> 6)) = a;
    }
}

// ---------------------------------------------------------------------------
// K1: degrees by popcount + scale arrays + layer-0 B operands.
// ---------------------------------------------------------------------------
__global__ __launch_bounds__(256) void k_scale0(const float* __restrict__ x,
        const u64* __restrict__ Apk, const u64* __restrict__ ATpk,
        float* __restrict__ dsu, float* __restrict__ dsi,
        u16* __restrict__ BuT, u16* __restrict__ BiT) {
    __shared__ float sc[64];
    const int t = threadIdx.x;
    const int r0 = blockIdx.x * 64;
    {
        const int rl = t >> 2, part = t & 3;
        int cnt = 0;
        if (r0 < NU) {
            const u64* p = Apk + (size_t)(r0 + rl) * 128 + part * 32;
            #pragma unroll
            for (int i = 0; i < 32; i++) cnt += (int)__popcll(p[i]);
        } else {
            const u64* p = ATpk + (size_t)(r0 - NU + rl) * 64 + part * 16;
            #pragma unroll
            for (int i = 0; i < 16; i++) cnt += (int)__popcll(p[i]);
        }
        cnt += __shfl_xor(cnt, 1, 64);
        cnt += __shfl_xor(cnt, 2, 64);
        if (part == 0) {
            float s = cnt > 0 ? rsqrtf((float)cnt) : 0.f;
            sc[rl] = s;
            if (r0 < NU) dsu[r0 + rl] = s; else dsi[r0 - NU + rl] = s;
        }
    }
    __syncthreads();
    const int r4 = t >> 4, c4 = t & 15;
    float y[4][4];
    #pragma unroll
    for (int j = 0; j < 4; j++) {
        const int rl = r4 * 4 + j;
        const float s = sc[rl];
        float4 xv = *(const float4*)(x + (size_t)(r0 + rl) * ND + c4 * 4);
        y[j][0] = xv.x * s; y[j][1] = xv.y * s;
        y[j][2] = xv.z * s; y[j][3] = xv.w * s;
    }
    u16* dst; size_t stride; int col0;
    if (r0 < NU) { dst = BuT; stride = NU; col0 = r0; }
    else         { dst = BiT; stride = NI; col0 = r0 - NU; }
    #pragma unroll
    for (int k = 0; k < 4; k++) {
        ushort4 w;
        w.x = f2bf(y[0][k]); w.y = f2bf(y[1][k]);
        w.z = f2bf(y[2][k]); w.w = f2bf(y[3][k]);
        *(ushort4*)(dst + (size_t)(c4 * 4 + k) * stride + col0 + r4 * 4) = w;
    }
}

// ---------------------------------------------------------------------------
// K2: fused split-K GEMM + last-finisher reduce. Each block computes its
// 64x64 partial and stores it; the LAST block to finish a tile (per-tile
// atomic counter, agent-scope release/acquire fences) reduces all chunks,
// applies scaling, writes acc/out, and emits next-layer operands.
// ---------------------------------------------------------------------------
__global__ __launch_bounds__(256) void k_gemmf(
        const u64* __restrict__ Apk, const u64* __restrict__ ATpk,
        const u16* __restrict__ BuT, const u16* __restrict__ BiT,
        float* __restrict__ Ptop, float* __restrict__ Pbot,
        const float* __restrict__ dsu, const float* __restrict__ dsi,
        float* __restrict__ accbuf, u16* __restrict__ BuTn,
        u16* __restrict__ BiTn, float* __restrict__ out,
        int* __restrict__ cnt, int layer) {
    __shared__ __align__(16) u16 Bs[64 * BROW];   // 66.6 KB (reused as stash/TB)
    __shared__ int isLast;
    const int t = threadIdx.x, bx = blockIdx.x;
    const int lane = t & 63, w = t >> 6, lr = lane & 15, lg = lane >> 4;
    const u64* arow; const u16* dense; int Kstr, wpr, kbase, pstr, tile, tileId, nch;
    float* Pout; bool top;
    if (bx < 1024) {
        tile = bx >> 3; const int chunk = bx & 7; top = true;
        arow = ATpk + (size_t)(tile * 64) * 64 + chunk * 8; wpr = 64;
        dense = BuT; Kstr = NU; kbase = chunk * 512; pstr = CT * 64;
        Pout = Ptop + (size_t)(tile * 64) * pstr + chunk * 64;
        tileId = tile; nch = CT;
    } else {
        const int b2 = bx - 1024; tile = b2 >> 4; const int chunk = b2 & 15; top = false;
        arow = Apk + (size_t)(tile * 64) * 128 + chunk * 8; wpr = 128;
        dense = BiT; Kstr = NI; kbase = chunk * 512; pstr = CB * 64;
        Pout = Pbot + (size_t)(tile * 64) * pstr + chunk * 64;
        tileId = 128 + tile; nch = CB;
    }
    // stage 64x512 dense chunk via wave-level DMA
    const u16* gsrc = dense + kbase;
    #pragma unroll
    for (int it = 0; it < 16; it++) {
        const int e = it * 4 + w;
        __builtin_amdgcn_global_load_lds(
            (const __attribute__((address_space(1))) void*)
                (gsrc + (size_t)e * Kstr + lane * 8),
            (__attribute__((address_space(3))) void*)(&Bs[e * BROW]),
            16, 0, 0);
    }
    const u64* myrow = arow + (size_t)(w * 16 + lr) * wpr;
    u64 aw[8];
    #pragma unroll
    for (int qq = 0; qq < 4; qq++) {
        ulonglong2 v = *(const ulonglong2*)(myrow + qq * 2);
        aw[qq * 2] = v.x; aw[qq * 2 + 1] = v.y;
    }
    f32x4 acc[4];
    #pragma unroll
    for (int i = 0; i < 4; i++) acc[i] = f32x4{0.f, 0.f, 0.f, 0.f};
    __syncthreads();

    #pragma unroll
    for (int kk = 0; kk < 8; kk++) {
        const u32 lo = (u32)aw[kk], hi = (u32)(aw[kk] >> 32);
        const u32 byte0 = (lo >> (lg * 8)) & 0xFFu;
        const u32 byte1 = (hi >> (lg * 8)) & 0xFFu;
        frag8 bf0, bf1;
        #pragma unroll
        for (int j = 0; j < 8; j++) {
            bf0[j] = (short)(((byte0 >> j) & 1u) ? 0x3F80 : 0);
            bf1[j] = (short)(((byte1 >> j) & 1u) ? 0x3F80 : 0);
        }
        #pragma unroll
        for (int nt = 0; nt < 4; nt++) {
            const int e = nt * 16 + lr;
            frag8 a0 = *(const frag8*)&Bs[e * BROW + kk * 64 + lg * 8];
            frag8 a1 = *(const frag8*)&Bs[e * BROW + kk * 64 + 32 + lg * 8];
            acc[nt] = __builtin_amdgcn_mfma_f32_16x16x32_bf16(a0, bf0, acc[nt], 0, 0, 0);
            acc[nt] = __builtin_amdgcn_mfma_f32_16x16x32_bf16(a1, bf1, acc[nt], 0, 0, 0);
        }
    }
    // stash tile in LDS (rotation-staggered), then coalesced partial stores
    __syncthreads();
    float* Fs = (float*)Bs;
    #pragma unroll
    for (int nt = 0; nt < 4; nt++) {
        const int row = w * 16 + lr, g = nt * 4 + lg;
        *(f32x4*)&Fs[row * 64 + (((g + row) & 15) * 4)] = acc[nt];
    }
    __syncthreads();
    #pragma unroll
    for (int ii = 0; ii < 4; ii++) {
        const int slot = t + ii * 256;
        const int row = slot >> 4, g = slot & 15;
        f32x4 v = *(const f32x4*)&Fs[row * 64 + (((g + row) & 15) * 4)];
        *(f32x4*)&Pout[(size_t)row * pstr + g * 4] = v;
    }
    __syncthreads();           // all stores issued & drained before fence
    if (t == 0) {
        __builtin_amdgcn_fence(__ATOMIC_RELEASE, "agent");
        int old = __hip_atomic_fetch_add(&cnt[tileId], 1,
                                         __ATOMIC_RELAXED, __HIP_MEMORY_SCOPE_AGENT);
        isLast = (old == nch - 1);
    }
    __syncthreads();
    if (!isLast) return;

    // -------- last-finisher: reduce this tile's chunks, scale, emit --------
    __builtin_amdgcn_fence(__ATOMIC_ACQUIRE, "agent");
    const int r = t >> 2, q = t & 3;     // row in tile, 16-embed quarter
    int grow; float so;
    float4 s0 = {0,0,0,0}, s1 = {0,0,0,0}, s2 = {0,0,0,0}, s3 = {0,0,0,0};
    if (top) {
        grow = tile * 64 + r;
        const float* p = Ptop + (size_t)grow * (CT * 64) + q * 16;
        #pragma unroll
        for (int c = 0; c < CT; c++) {
            s0.x += p[c*64+0];  s0.y += p[c*64+1];  s0.z += p[c*64+2];  s0.w += p[c*64+3];
            s1.x += p[c*64+4];  s1.y += p[c*64+5];  s1.z += p[c*64+6];  s1.w += p[c*64+7];
            s2.x += p[c*64+8];  s2.y += p[c*64+9];  s2.z += p[c*64+10]; s2.w += p[c*64+11];
            s3.x += p[c*64+12]; s3.y += p[c*64+13]; s3.z += p[c*64+14]; s3.w += p[c*64+15];
        }
        so = dsi[grow];
    } else {
        const int u = tile * 64 + r;
        grow = NI + u;
        const float* p = Pbot + (size_t)u * (CB * 64) + q * 16;
        #pragma unroll
        for (int c = 0; c < CB; c++) {
            s0.x += p[c*64+0];  s0.y += p[c*64+1];  s0.z += p[c*64+2];  s0.w += p[c*64+3];
            s1.x += p[c*64+4];  s1.y += p[c*64+5];  s1.z += p[c*64+6];  s1.w += p[c*64+7];
            s2.x += p[c*64+8];  s2.y += p[c*64+9];  s2.z += p[c*64+10]; s2.w += p[c*64+11];
            s3.x += p[c*64+12]; s3.y += p[c*64+13]; s3.z += p[c*64+14]; s3.w += p[c*64+15];
        }
        so = dsu[u];
    }
    float4 y[4];
    y[0].x = s0.x*so; y[0].y = s0.y*so; y[0].z = s0.z*so; y[0].w = s0.w*so;
    y[1].x = s1.x*so; y[1].y = s1.y*so; y[1].z = s1.z*so; y[1].w = s1.w*so;
    y[2].x = s2.x*so; y[2].y = s2.y*so; y[2].z = s2.z*so; y[2].w = s2.w*so;
    y[3].x = s3.x*so; y[3].y = s3.y*so; y[3].z = s3.z*so; y[3].w = s3.w*so;
    #pragma unroll
    for (int j = 0; j < 4; j++) {
        const size_t o = (size_t)grow * ND + q * 16 + j * 4;
        if (layer == 0) {
            *(float4*)(accbuf + o) = y[j];
        } else if (layer == 1) {
            float4 a = *(const float4*)(accbuf + o);
            a.x += y[j].x; a.y += y[j].y; a.z += y[j].z; a.w += y[j].w;
            *(float4*)(accbuf + o) = a;
        } else {
            float4 a = *(const float4*)(accbuf + o);
            a.x = (a.x + y[j].x) * 0.25f; a.y = (a.y + y[j].y) * 0.25f;
            a.z = (a.z + y[j].z) * 0.25f; a.w = (a.w + y[j].w) * 0.25f;
            *(float4*)(out + o) = a;
        }
    }
    if (layer != 2) {
        const float fn = (grow < NU) ? dsu[grow] : dsi[grow - NU];
        u16* TB = (u16*)Bs;              // [64 emb][72]
        #pragma unroll
        for (int j = 0; j < 4; j++) {
            TB[(q * 16 + j * 4 + 0) * 72 + r] = f2bf(y[j].x * fn);
            TB[(q * 16 + j * 4 + 1) * 72 + r] = f2bf(y[j].y * fn);
            TB[(q * 16 + j * 4 + 2) * 72 + r] = f2bf(y[j].z * fn);
            TB[(q * 16 + j * 4 + 3) * 72 + r] = f2bf(y[j].w * fn);
        }
        __syncthreads();
        u16* dst; size_t stride; int col0;
        if (top) {
            if (tile < 64) { dst = BuTn; stride = NU; col0 = tile * 64; }
            else           { dst = BiTn; stride = NI; col0 = tile * 64 - NU; }
        } else             { dst = BiTn; stride = NI; col0 = (NI - NU) + tile * 64; }
        const int n = t >> 2, part = t & 3;
        uint4 a = *(const uint4*)&TB[n * 72 + part * 16];
        uint4 b = *(const uint4*)&TB[n * 72 + part * 16 + 8];
        *(uint4*)(dst + (size_t)n * stride + col0 + part * 16) = a;
        *(uint4*)(dst + (size_t)n * stride + col0 + part * 16 + 8) = b;
    }
}

extern "C" void kernel_launch(void* const* d_in, const int* in_sizes, int n_in,
                              void* d_out, int out_size, void* d_ws, size_t ws_size,
                              hipStream_t stream) {
    (void)in_sizes; (void)n_in; (void)out_size; (void)ws_size;
    const float* x    = (const float*)d_in[0];
    const int*   edge = (const int*)d_in[1];
    float* out = (float*)d_out;

    char* ws = (char*)d_ws;
    size_t off = 0;
    u64* Apk  = (u64*)(ws + off); off += (size_t)NU * (NI / 64) * 8;   // 4 MiB
    u64* ATpk = (u64*)(ws + off); off += (size_t)NI * (NU / 64) * 8;   // 4 MiB
    float* dsu = (float*)(ws + off); off += (size_t)NU * 4;
    float* dsi = (float*)(ws + off); off += (size_t)NI * 4;
    u16* BuT0 = (u16*)(ws + off); off += (size_t)ND * NU * 2;
    u16* BuT1 = (u16*)(ws + off); off += (size_t)ND * NU * 2;
    u16* BiT0 = (u16*)(ws + off); off += (size_t)ND * NI * 2;
    u16* BiT1 = (u16*)(ws + off); off += (size_t)ND * NI * 2;
    float* acc  = (float*)(ws + off); off += (size_t)NTOT * ND * 4;
    float* Ptop = (float*)(ws + off); off += (size_t)NI * CT * 64 * 4; // 16 MiB
    float* Pbot = (float*)(ws + off); off += (size_t)NU * CB * 64 * 4; // 16 MiB
    int* cnt = (int*)(ws + off); off += (size_t)3 * NTILE * 4;

    hipMemsetAsync(cnt, 0, 3 * NTILE * sizeof(int), stream);
    k_pack2<<<512, 256, 0, stream>>>(edge, Apk, ATpk);
    k_scale0<<<NTOT / 64, 256, 0, stream>>>(x, Apk, ATpk, dsu, dsi, BuT0, BiT0);

    k_gemmf<<<2048, 256, 0, stream>>>(Apk, ATpk, BuT0, BiT0, Ptop, Pbot,
                                      dsu, dsi, acc, BuT1, BiT1, out, cnt, 0);
    k_gemmf<<<2048, 256, 0, stream>>>(Apk, ATpk, BuT1, BiT1, Ptop, Pbot,
                                      dsu, dsi, acc, BuT0, BiT0, out, cnt + NTILE, 1);
    k_gemmf<<<2048, 256, 0, stream>>>(Apk, ATpk, BuT0, BiT0, Ptop, Pbot,
                                      dsu, dsi, acc, (u16*)nullptr, (u16*)nullptr,
                                      out, cnt + 2 * NTILE, 2);
}

// Round 9
// 458.717 us; speedup vs baseline: 1.5165x; 1.5165x over previous
//
#include <hip/hip_runtime.h>

#define NU 4096
#define NI 8192
#define ND 64
#define NTOT 12288
#define CT 8           // top split-K chunks  (K=NU,  ck=512)
#define CB 16          // bottom split-K chunks (K=NI, ck=512)

typedef unsigned short u16;
typedef unsigned int u32;
typedef unsigned long long u64;

__device__ __forceinline__ u16 f2bf(float f) {
    union { float f; u32 u; } v; v.f = f;
    u32 u = v.u;
    u += 0x7FFFu + ((u >> 16) & 1u);   // round-to-nearest-even
    return (u16)(u >> 16);
}

typedef short frag8 __attribute__((ext_vector_type(8)));
typedef float f32x4 __attribute__((ext_vector_type(4)));

// ---------------------------------------------------------------------------
// K0: edge (int32 0/1) -> bit-packed A AND AT. 512 blocks (2/CU) of
// 128 rows x 512 cols.
// ---------------------------------------------------------------------------
__global__ __launch_bounds__(256) void k_pack2(const int* __restrict__ edge,
        u64* __restrict__ Apk, u64* __restrict__ ATpk) {
    __shared__ __align__(16) u16 At[128][40];   // 10 KB
    __shared__ __align__(16) u64 Tt[512][2];    // 8 KB
    const int t = threadIdx.x;
    const int u0 = (blockIdx.x >> 4) * 128;
    const int i0 = (blockIdx.x & 15) * 512;
    const int cg = t & 31;          // 16-col group
    const int rb = t >> 5;          // row-group (16 rows each)

    #pragma unroll 4
    for (int rr = 0; rr < 16; rr++) {
        const int row = rb * 16 + rr;
        const int4* p = (const int4*)(edge + (size_t)(u0 + row) * NI + i0 + cg * 16);
        u32 bits = 0;
        #pragma unroll
        for (int m = 0; m < 4; m++) {
            int4 v = p[m];
            bits |= (v.x != 0 ? 1u : 0u) << (m * 4 + 0);
            bits |= (v.y != 0 ? 1u : 0u) << (m * 4 + 1);
            bits |= (v.z != 0 ? 1u : 0u) << (m * 4 + 2);
            bits |= (v.w != 0 ? 1u : 0u) << (m * 4 + 3);
        }
        At[row][cg] = (u16)bits;
    }
    __syncthreads();

    {   // Apk store: 32 B per thread (2 x uint4), fully coalesced
        const int row = t >> 1, h = t & 1;
        uint4 v0 = *(const uint4*)&At[row][h * 16];
        uint4 v1 = *(const uint4*)&At[row][h * 16 + 8];
        u64* dst = Apk + (size_t)(u0 + row) * 128 + (i0 >> 6) + h * 4;
        *(uint4*)dst = v0;
        *(uint4*)(dst + 2) = v1;
    }

    {   // 64x64 bit-transpose subtiles (2 row-subtiles x 8 col-subtiles)
        const int lane = t & 63, w = t >> 6;
        const u64 M[6] = {0x00000000FFFFFFFFULL, 0x0000FFFF0000FFFFULL,
                          0x00FF00FF00FF00FFULL, 0x0F0F0F0F0F0F0F0FULL,
                          0x3333333333333333ULL, 0x5555555555555555ULL};
        #pragma unroll
        for (int m = 0; m < 4; m++) {
            const int id = m * 4 + w;
            const int sr = id >> 3, sc = id & 7;
            u64 x = *(const u64*)&At[sr * 64 + lane][sc * 4];
            #pragma unroll
            for (int si = 0; si < 6; si++) {
                const int s = 32 >> si;
                u64 y = __shfl_xor(x, s, 64);
                x = (lane & s) ? ((x & ~M[si]) | ((y >> s) & M[si]))
                               : ((x &  M[si]) | ((y << s) & ~M[si]));
            }
            Tt[sc * 64 + lane][sr] = x;
        }
    }
    __syncthreads();
    #pragma unroll
    for (int j = 0; j < 2; j++) {
        const int item = t * 2 + j;
        ulonglong2 a = *(const ulonglong2*)&Tt[item][0];
        *(ulonglong2*)(ATpk + (size_t)(i0 + item) * 64 + (u0 >> 6)) = a;
    }
}

// ---------------------------------------------------------------------------
// K1: degrees by popcount + scale arrays + layer-0 B operands.
// ---------------------------------------------------------------------------
__global__ __launch_bounds__(256) void k_scale0(const float* __restrict__ x,
        const u64* __restrict__ Apk, const u64* __restrict__ ATpk,
        float* __restrict__ dsu, float* __restrict__ dsi,
        u16* __restrict__ BuT, u16* __restrict__ BiT) {
    __shared__ float sc[64];
    const int t = threadIdx.x;
    const int r0 = blockIdx.x * 64;
    {
        const int rl = t >> 2, part = t & 3;
        int cnt = 0;
        if (r0 < NU) {
            const u64* p = Apk + (size_t)(r0 + rl) * 128 + part * 32;
            #pragma unroll
            for (int i = 0; i < 32; i++) cnt += (int)__popcll(p[i]);
        } else {
            const u64* p = ATpk + (size_t)(r0 - NU + rl) * 64 + part * 16;
            #pragma unroll
            for (int i = 0; i < 16; i++) cnt += (int)__popcll(p[i]);
        }
        cnt += __shfl_xor(cnt, 1, 64);
        cnt += __shfl_xor(cnt, 2, 64);
        if (part == 0) {
            float s = cnt > 0 ? rsqrtf((float)cnt) : 0.f;
            sc[rl] = s;
            if (r0 < NU) dsu[r0 + rl] = s; else dsi[r0 - NU + rl] = s;
        }
    }
    __syncthreads();
    const int r4 = t >> 4, c4 = t & 15;
    float y[4][4];
    #pragma unroll
    for (int j = 0; j < 4; j++) {
        const int rl = r4 * 4 + j;
        const float s = sc[rl];
        float4 xv = *(const float4*)(x + (size_t)(r0 + rl) * ND + c4 * 4);
        y[j][0] = xv.x * s; y[j][1] = xv.y * s;
        y[j][2] = xv.z * s; y[j][3] = xv.w * s;
    }
    u16* dst; size_t stride; int col0;
    if (r0 < NU) { dst = BuT; stride = NU; col0 = r0; }
    else         { dst = BiT; stride = NI; col0 = r0 - NU; }
    #pragma unroll
    for (int k = 0; k < 4; k++) {
        ushort4 w;
        w.x = f2bf(y[0][k]); w.y = f2bf(y[1][k]);
        w.z = f2bf(y[2][k]); w.w = f2bf(y[3][k]);
        *(ushort4*)(dst + (size_t)(c4 * 4 + k) * stride + col0 + r4 * 4) = w;
    }
}

// ---------------------------------------------------------------------------
// K2: split-K GEMM, register-direct fragments. Dense operand (0.5/1 MB,
// L2-resident) loaded straight global->VGPR per MFMA fragment: no staging
// LDS, no staging barrier, no LDS bank conflicts. Adjacency bits register-
// held. Epilogue: 16 KB LDS stash -> 1KB-coalesced chunk-minor partials.
// ---------------------------------------------------------------------------
__global__ __launch_bounds__(256) void k_gemm(
        const u64* __restrict__ Apk, const u64* __restrict__ ATpk,
        const u16* __restrict__ BuT, const u16* __restrict__ BiT,
        float* __restrict__ Ptop, float* __restrict__ Pbot) {
    __shared__ __align__(16) float Fs[64 * 64];   // 16 KB epilogue stash
    const int t = threadIdx.x, bx = blockIdx.x;
    const int lane = t & 63, w = t >> 6, lr = lane & 15, lg = lane >> 4;
    const u64* arow; const u16* dense; int Kstr, wpr, kbase, pstr; float* Pout;
    if (bx < 1024) {
        const int tile = bx >> 3, chunk = bx & 7;
        arow = ATpk + (size_t)(tile * 64) * 64 + chunk * 8; wpr = 64;
        dense = BuT; Kstr = NU; kbase = chunk * 512; pstr = CT * 64;
        Pout = Ptop + (size_t)(tile * 64) * pstr + chunk * 64;
    } else {
        const int b2 = bx - 1024, tile = b2 >> 4, chunk = b2 & 15;
        arow = Apk + (size_t)(tile * 64) * 128 + chunk * 8; wpr = 128;
        dense = BiT; Kstr = NI; kbase = chunk * 512; pstr = CB * 64;
        Pout = Pbot + (size_t)(tile * 64) * pstr + chunk * 64;
    }
    // preload this wave's 16 rows x 8 adjacency words (one row per lr lane)
    const u64* myrow = arow + (size_t)(w * 16 + lr) * wpr;
    u64 aw[8];
    #pragma unroll
    for (int qq = 0; qq < 4; qq++) {
        ulonglong2 v = *(const ulonglong2*)(myrow + qq * 2);
        aw[qq * 2] = v.x; aw[qq * 2 + 1] = v.y;
    }
    // per-nt dense base pointers (embed row e = nt*16+lr, this lane's lg slice)
    const u16* pb[4];
    #pragma unroll
    for (int nt = 0; nt < 4; nt++)
        pb[nt] = dense + (size_t)(nt * 16 + lr) * Kstr + kbase + lg * 8;

    f32x4 acc[4];
    #pragma unroll
    for (int i = 0; i < 4; i++) acc[i] = f32x4{0.f, 0.f, 0.f, 0.f};

    #pragma unroll
    for (int kk = 0; kk < 8; kk++) {
        const u32 lo = (u32)aw[kk], hi = (u32)(aw[kk] >> 32);
        const u32 byte0 = (lo >> (lg * 8)) & 0xFFu;
        const u32 byte1 = (hi >> (lg * 8)) & 0xFFu;
        frag8 bf0, bf1;
        #pragma unroll
        for (int j = 0; j < 8; j++) {
            bf0[j] = (short)(((byte0 >> j) & 1u) ? 0x3F80 : 0);
            bf1[j] = (short)(((byte1 >> j) & 1u) ? 0x3F80 : 0);
        }
        #pragma unroll
        for (int nt = 0; nt < 4; nt++) {
            frag8 a0 = *(const frag8*)(pb[nt] + kk * 64);
            frag8 a1 = *(const frag8*)(pb[nt] + kk * 64 + 32);
            acc[nt] = __builtin_amdgcn_mfma_f32_16x16x32_bf16(a0, bf0, acc[nt], 0, 0, 0);
            acc[nt] = __builtin_amdgcn_mfma_f32_16x16x32_bf16(a1, bf1, acc[nt], 0, 0, 0);
        }
    }
    // stash tile in LDS (rotation-staggered granules), then coalesced stores
    // D layout: lane holds output-row w*16+lr, embeds nt*16+lg*4..+3
    #pragma unroll
    for (int nt = 0; nt < 4; nt++) {
        const int row = w * 16 + lr, g = nt * 4 + lg;
        *(f32x4*)&Fs[row * 64 + (((g + row) & 15) * 4)] = acc[nt];
    }
    __syncthreads();
    #pragma unroll
    for (int ii = 0; ii < 4; ii++) {
        const int slot = t + ii * 256;
        const int row = slot >> 4, g = slot & 15;
        f32x4 v = *(const f32x4*)&Fs[row * 64 + (((g + row) & 15) * 4)];
        *(f32x4*)&Pout[(size_t)row * pstr + g * 4] = v;
    }
}

// ---------------------------------------------------------------------------
// K3: reduce partials (chunk-minor layout: per-row data fully contiguous),
// apply output scale, acc/out logic, emit next-layer B operands.
// ---------------------------------------------------------------------------
__global__ __launch_bounds__(256) void k_reduce(
        const float* __restrict__ Ptop, const float* __restrict__ Pbot,
        const float* __restrict__ dsu, const float* __restrict__ dsi,
        float* __restrict__ accbuf, u16* __restrict__ BuTn,
        u16* __restrict__ BiTn, float* __restrict__ out, int layer) {
    __shared__ u16 TB[64][24];
    const int t = threadIdx.x, bx = blockIdx.x;
    const int rl = t >> 4, e4 = t & 15;
    int grow; float so;
    float sx = 0.f, sy = 0.f, sz = 0.f, sw = 0.f;
    if (bx < 512) {
        grow = bx * 16 + rl;
        const float* p = Ptop + (size_t)grow * (CT * 64) + e4 * 4;
        #pragma unroll
        for (int c = 0; c < CT; c++) {
            float4 v = *(const float4*)(p + c * 64);
            sx += v.x; sy += v.y; sz += v.z; sw += v.w;
        }
        so = dsi[grow];
    } else {
        const int u = (bx - 512) * 16 + rl;
        grow = NI + u;
        const float* p = Pbot + (size_t)u * (CB * 64) + e4 * 4;
        #pragma unroll
        for (int c = 0; c < CB; c++) {
            float4 v = *(const float4*)(p + c * 64);
            sx += v.x; sy += v.y; sz += v.z; sw += v.w;
        }
        so = dsu[grow - NI];
    }
    float4 y;
    y.x = sx * so; y.y = sy * so; y.z = sz * so; y.w = sw * so;
    const size_t o = (size_t)grow * ND + e4 * 4;
    if (layer == 0) {
        *(float4*)(accbuf + o) = y;
    } else if (layer == 1) {
        float4 a = *(const float4*)(accbuf + o);
        a.x += y.x; a.y += y.y; a.z += y.z; a.w += y.w;
        *(float4*)(accbuf + o) = a;
    } else {
        float4 a = *(const float4*)(accbuf + o);
        a.x = (a.x + y.x) * 0.25f; a.y = (a.y + y.y) * 0.25f;
        a.z = (a.z + y.z) * 0.25f; a.w = (a.w + y.w) * 0.25f;
        *(float4*)(out + o) = a;
    }
    if (layer != 2) {
        const float fn = (grow < NU) ? dsu[grow] : dsi[grow - NU];
        TB[e4 * 4 + 0][rl] = f2bf(y.x * fn);
        TB[e4 * 4 + 1][rl] = f2bf(y.y * fn);
        TB[e4 * 4 + 2][rl] = f2bf(y.z * fn);
        TB[e4 * 4 + 3][rl] = f2bf(y.w * fn);
        __syncthreads();
        if (t < 128) {
            const int e = t >> 1, h = t & 1;
            u16* dst; size_t stride; int col0;
            if (bx < 256)      { dst = BuTn; stride = NU; col0 = bx * 16; }
            else if (bx < 512) { dst = BiTn; stride = NI; col0 = bx * 16 - NU; }
            else               { dst = BiTn; stride = NI; col0 = (bx - 512) * 16 + NI - NU; }
            uint4 v = *(const uint4*)&TB[e][h * 8];
            *(uint4*)(dst + (size_t)e * stride + col0 + h * 8) = v;
        }
    }
}

extern "C" void kernel_launch(void* const* d_in, const int* in_sizes, int n_in,
                              void* d_out, int out_size, void* d_ws, size_t ws_size,
                              hipStream_t stream) {
    (void)in_sizes; (void)n_in; (void)out_size; (void)ws_size;
    const float* x    = (const float*)d_in[0];
    const int*   edge = (const int*)d_in[1];
    float* out = (float*)d_out;

    char* ws = (char*)d_ws;
    size_t off = 0;
    u64* Apk  = (u64*)(ws + off); off += (size_t)NU * (NI / 64) * 8;   // 4 MiB
    u64* ATpk = (u64*)(ws + off); off += (size_t)NI * (NU / 64) * 8;   // 4 MiB
    float* dsu = (float*)(ws + off); off += (size_t)NU * 4;
    float* dsi = (float*)(ws + off); off += (size_t)NI * 4;
    u16* BuT0 = (u16*)(ws + off); off += (size_t)ND * NU * 2;
    u16* BuT1 = (u16*)(ws + off); off += (size_t)ND * NU * 2;
    u16* BiT0 = (u16*)(ws + off); off += (size_t)ND * NI * 2;
    u16* BiT1 = (u16*)(ws + off); off += (size_t)ND * NI * 2;
    float* acc  = (float*)(ws + off); off += (size_t)NTOT * ND * 4;
    float* Ptop = (float*)(ws + off); off += (size_t)NI * CT * 64 * 4; // 16 MiB
    float* Pbot = (float*)(ws + off); off += (size_t)NU * CB * 64 * 4; // 16 MiB

    k_pack2<<<512, 256, 0, stream>>>(edge, Apk, ATpk);
    k_scale0<<<NTOT / 64, 256, 0, stream>>>(x, Apk, ATpk, dsu, dsi, BuT0, BiT0);

    k_gemm<<<2048, 256, 0, stream>>>(Apk, ATpk, BuT0, BiT0, Ptop, Pbot);
    k_reduce<<<768, 256, 0, stream>>>(Ptop, Pbot, dsu, dsi, acc, BuT1, BiT1, out, 0);
    k_gemm<<<2048, 256, 0, stream>>>(Apk, ATpk, BuT1, BiT1, Ptop, Pbot);
    k_reduce<<<768, 256, 0, stream>>>(Ptop, Pbot, dsu, dsi, acc, BuT0, BiT0, out, 1);
    k_gemm<<<2048, 256, 0, stream>>>(Apk, ATpk, BuT0, BiT0, Ptop, Pbot);
    k_reduce<<<768, 256, 0, stream>>>(Ptop, Pbot, dsu, dsi, acc,
                                      (u16*)nullptr, (u16*)nullptr, out, 2);
}

// Round 10
// 293.691 us; speedup vs baseline: 2.3686x; 1.5619x over previous
//
#include <hip/hip_runtime.h>

#define NU 4096
#define NI 8192
#define ND 64
#define NTOT 12288
#define CT 8           // top split-K chunks  (K=NU,  ck=512)
#define CB 16          // bottom split-K chunks (K=NI, ck=512)

typedef unsigned short u16;
typedef unsigned int u32;
typedef unsigned long long u64;

__device__ __forceinline__ u16 f2bf(float f) {
    union { float f; u32 u; } v; v.f = f;
    u32 u = v.u;
    u += 0x7FFFu + ((u >> 16) & 1u);   // round-to-nearest-even
    return (u16)(u >> 16);
}

typedef short frag8 __attribute__((ext_vector_type(8)));
typedef float f32x4 __attribute__((ext_vector_type(4)));

// Fragment-major dense operand layout, u16 units:
//   off(c,kk,nt,q,lr,j) = (c*8+kk)*4096 + nt*1024 + q*128 + lr*8 + j
// (c = k/512, kk = (k%512)/64, q = (k%64)/8, j = k%8; e = nt*16+lr)
// A wave's MFMA A-frag (kk, half h, row-group nt) = contiguous 1 KB at
//   chunkbase + (kk*4+nt)*1024 + h*512 + lane*8.

// ---------------------------------------------------------------------------
// K0: edge (int32 0/1) -> bit-packed A AND AT. 512 blocks of 128 x 512.
// ---------------------------------------------------------------------------
__global__ __launch_bounds__(256) void k_pack2(const int* __restrict__ edge,
        u64* __restrict__ Apk, u64* __restrict__ ATpk) {
    __shared__ __align__(16) u16 At[128][40];   // 10 KB
    __shared__ __align__(16) u64 Tt[512][2];    // 8 KB
    const int t = threadIdx.x;
    const int u0 = (blockIdx.x >> 4) * 128;
    const int i0 = (blockIdx.x & 15) * 512;
    const int cg = t & 31;
    const int rb = t >> 5;

    #pragma unroll 4
    for (int rr = 0; rr < 16; rr++) {
        const int row = rb * 16 + rr;
        const int4* p = (const int4*)(edge + (size_t)(u0 + row) * NI + i0 + cg * 16);
        u32 bits = 0;
        #pragma unroll
        for (int m = 0; m < 4; m++) {
            int4 v = p[m];
            bits |= (v.x != 0 ? 1u : 0u) << (m * 4 + 0);
            bits |= (v.y != 0 ? 1u : 0u) << (m * 4 + 1);
            bits |= (v.z != 0 ? 1u : 0u) << (m * 4 + 2);
            bits |= (v.w != 0 ? 1u : 0u) << (m * 4 + 3);
        }
        At[row][cg] = (u16)bits;
    }
    __syncthreads();

    {   // Apk store: 32 B per thread (2 x uint4), fully coalesced
        const int row = t >> 1, h = t & 1;
        uint4 v0 = *(const uint4*)&At[row][h * 16];
        uint4 v1 = *(const uint4*)&At[row][h * 16 + 8];
        u64* dst = Apk + (size_t)(u0 + row) * 128 + (i0 >> 6) + h * 4;
        *(uint4*)dst = v0;
        *(uint4*)(dst + 2) = v1;
    }

    {   // 64x64 bit-transpose subtiles
        const int lane = t & 63, w = t >> 6;
        const u64 M[6] = {0x00000000FFFFFFFFULL, 0x0000FFFF0000FFFFULL,
                          0x00FF00FF00FF00FFULL, 0x0F0F0F0F0F0F0F0FULL,
                          0x3333333333333333ULL, 0x5555555555555555ULL};
        #pragma unroll
        for (int m = 0; m < 4; m++) {
            const int id = m * 4 + w;
            const int sr = id >> 3, sc = id & 7;
            u64 x = *(const u64*)&At[sr * 64 + lane][sc * 4];
            #pragma unroll
            for (int si = 0; si < 6; si++) {
                const int s = 32 >> si;
                u64 y = __shfl_xor(x, s, 64);
                x = (lane & s) ? ((x & ~M[si]) | ((y >> s) & M[si]))
                               : ((x &  M[si]) | ((y << s) & ~M[si]));
            }
            Tt[sc * 64 + lane][sr] = x;
        }
    }
    __syncthreads();
    #pragma unroll
    for (int j = 0; j < 2; j++) {
        const int item = t * 2 + j;
        ulonglong2 a = *(const ulonglong2*)&Tt[item][0];
        *(ulonglong2*)(ATpk + (size_t)(i0 + item) * 64 + (u0 >> 6)) = a;
    }
}

// ---------------------------------------------------------------------------
// K1: degrees by popcount + scale arrays + layer-0 operands (frag-major).
// ---------------------------------------------------------------------------
__global__ __launch_bounds__(256) void k_scale0(const float* __restrict__ x,
        const u64* __restrict__ Apk, const u64* __restrict__ ATpk,
        float* __restrict__ dsu, float* __restrict__ dsi,
        u16* __restrict__ BuF, u16* __restrict__ BiF) {
    __shared__ float sc[64];
    __shared__ __align__(16) u16 SB[64][72];   // [embed][node], 144-B rows
    const int t = threadIdx.x;
    const int r0 = blockIdx.x * 64;
    {
        const int rl = t >> 2, part = t & 3;
        int cnt = 0;
        if (r0 < NU) {
            const u64* p = Apk + (size_t)(r0 + rl) * 128 + part * 32;
            #pragma unroll
            for (int i = 0; i < 32; i++) cnt += (int)__popcll(p[i]);
        } else {
            const u64* p = ATpk + (size_t)(r0 - NU + rl) * 64 + part * 16;
            #pragma unroll
            for (int i = 0; i < 16; i++) cnt += (int)__popcll(p[i]);
        }
        cnt += __shfl_xor(cnt, 1, 64);
        cnt += __shfl_xor(cnt, 2, 64);
        if (part == 0) {
            float s = cnt > 0 ? rsqrtf((float)cnt) : 0.f;
            sc[rl] = s;
            if (r0 < NU) dsu[r0 + rl] = s; else dsi[r0 - NU + rl] = s;
        }
    }
    __syncthreads();
    const int r4 = t >> 4, c4 = t & 15;
    #pragma unroll
    for (int j = 0; j < 4; j++) {
        const int rl = r4 * 4 + j;
        const float s = sc[rl];
        float4 xv = *(const float4*)(x + (size_t)(r0 + rl) * ND + c4 * 4);
        SB[c4 * 4 + 0][rl] = f2bf(xv.x * s);
        SB[c4 * 4 + 1][rl] = f2bf(xv.y * s);
        SB[c4 * 4 + 2][rl] = f2bf(xv.z * s);
        SB[c4 * 4 + 3][rl] = f2bf(xv.w * s);
    }
    __syncthreads();
    u16* dstF; int nb;
    if (r0 < NU) { dstF = BuF; nb = r0; } else { dstF = BiF; nb = r0 - NU; }
    const size_t cb = (size_t)(((nb >> 9) << 3) + ((nb >> 6) & 7)) * 4096;
    #pragma unroll
    for (int gi = 0; gi < 2; gi++) {
        const int g = t * 2 + gi;
        const int e = g >> 3, q = g & 7;
        uint4 v = *(const uint4*)&SB[e][q * 8];
        *(uint4*)&dstF[cb + (size_t)(e >> 4) * 1024 + q * 128 + (e & 15) * 8] = v;
    }
}

// ---------------------------------------------------------------------------
// K2: split-K GEMM. Dense operand frag-major -> every MFMA A-frag load is
// a contiguous 1 KB wave load (lane*16 B). No staging LDS, no K-loop
// barriers. Adjacency bits register-held. Epilogue: 16 KB LDS stash ->
// 1KB-coalesced chunk-minor partial stores.
// ---------------------------------------------------------------------------
__global__ __launch_bounds__(256) void k_gemm(
        const u64* __restrict__ Apk, const u64* __restrict__ ATpk,
        const u16* __restrict__ BuF, const u16* __restrict__ BiF,
        float* __restrict__ Ptop, float* __restrict__ Pbot) {
    __shared__ __align__(16) float Fs[64 * 64];   // 16 KB epilogue stash
    const int t = threadIdx.x, bx = blockIdx.x;
    const int lane = t & 63, w = t >> 6, lr = lane & 15, lg = lane >> 4;
    const u64* arow; const u16* denseF; int wpr, pstr; float* Pout;
    if (bx < 1024) {
        const int tile = bx >> 3, chunk = bx & 7;
        arow = ATpk + (size_t)(tile * 64) * 64 + chunk * 8; wpr = 64;
        denseF = BuF + (size_t)chunk * 32768; pstr = CT * 64;
        Pout = Ptop + (size_t)(tile * 64) * pstr + chunk * 64;
    } else {
        const int b2 = bx - 1024, tile = b2 >> 4, chunk = b2 & 15;
        arow = Apk + (size_t)(tile * 64) * 128 + chunk * 8; wpr = 128;
        denseF = BiF + (size_t)chunk * 32768; pstr = CB * 64;
        Pout = Pbot + (size_t)(tile * 64) * pstr + chunk * 64;
    }
    // preload this wave's 16 rows x 8 adjacency words (one row per lr lane)
    const u64* myrow = arow + (size_t)(w * 16 + lr) * wpr;
    u64 aw[8];
    #pragma unroll
    for (int qq = 0; qq < 4; qq++) {
        ulonglong2 v = *(const ulonglong2*)(myrow + qq * 2);
        aw[qq * 2] = v.x; aw[qq * 2 + 1] = v.y;
    }
    const u16* pl = denseF + lane * 8;   // all frag loads: pl + uniform offset

    f32x4 acc[4];
    #pragma unroll
    for (int i = 0; i < 4; i++) acc[i] = f32x4{0.f, 0.f, 0.f, 0.f};

    #pragma unroll
    for (int kk = 0; kk < 8; kk++) {
        const u32 lo = (u32)aw[kk], hi = (u32)(aw[kk] >> 32);
        const u32 byte0 = (lo >> (lg * 8)) & 0xFFu;
        const u32 byte1 = (hi >> (lg * 8)) & 0xFFu;
        frag8 bf0, bf1;
        #pragma unroll
        for (int j = 0; j < 8; j++) {
            bf0[j] = (short)(((byte0 >> j) & 1u) ? 0x3F80 : 0);
            bf1[j] = (short)(((byte1 >> j) & 1u) ? 0x3F80 : 0);
        }
        #pragma unroll
        for (int nt = 0; nt < 4; nt++) {
            frag8 a0 = *(const frag8*)(pl + (size_t)(kk * 4 + nt) * 1024);
            frag8 a1 = *(const frag8*)(pl + (size_t)(kk * 4 + nt) * 1024 + 512);
            acc[nt] = __builtin_amdgcn_mfma_f32_16x16x32_bf16(a0, bf0, acc[nt], 0, 0, 0);
            acc[nt] = __builtin_amdgcn_mfma_f32_16x16x32_bf16(a1, bf1, acc[nt], 0, 0, 0);
        }
    }
    // stash tile in LDS (rotation-staggered granules), then coalesced stores
    #pragma unroll
    for (int nt = 0; nt < 4; nt++) {
        const int row = w * 16 + lr, g = nt * 4 + lg;
        *(f32x4*)&Fs[row * 64 + (((g + row) & 15) * 4)] = acc[nt];
    }
    __syncthreads();
    #pragma unroll
    for (int ii = 0; ii < 4; ii++) {
        const int slot = t + ii * 256;
        const int row = slot >> 4, g = slot & 15;
        f32x4 v = *(const f32x4*)&Fs[row * 64 + (((g + row) & 15) * 4)];
        *(f32x4*)&Pout[(size_t)row * pstr + g * 4] = v;
    }
}

// ---------------------------------------------------------------------------
// K3: reduce partials (chunk-minor, contiguous per row), apply output scale,
// acc/out logic, emit next-layer operands in frag-major layout.
// ---------------------------------------------------------------------------
__global__ __launch_bounds__(256) void k_reduce(
        const float* __restrict__ Ptop, const float* __restrict__ Pbot,
        const float* __restrict__ dsu, const float* __restrict__ dsi,
        float* __restrict__ accbuf, u16* __restrict__ BuFn,
        u16* __restrict__ BiFn, float* __restrict__ out, int layer) {
    __shared__ __align__(16) u16 TB[64][24];   // [embed][node], 48-B rows
    const int t = threadIdx.x, bx = blockIdx.x;
    const int rl = t >> 4, e4 = t & 15;
    int grow; float so;
    float sx = 0.f, sy = 0.f, sz = 0.f, sw = 0.f;
    if (bx < 512) {
        grow = bx * 16 + rl;
        const float* p = Ptop + (size_t)grow * (CT * 64) + e4 * 4;
        #pragma unroll
        for (int c = 0; c < CT; c++) {
            float4 v = *(const float4*)(p + c * 64);
            sx += v.x; sy += v.y; sz += v.z; sw += v.w;
        }
        so = dsi[grow];
    } else {
        const int u = (bx - 512) * 16 + rl;
        grow = NI + u;
        const float* p = Pbot + (size_t)u * (CB * 64) + e4 * 4;
        #pragma unroll
        for (int c = 0; c < CB; c++) {
            float4 v = *(const float4*)(p + c * 64);
            sx += v.x; sy += v.y; sz += v.z; sw += v.w;
        }
        so = dsu[grow - NI];
    }
    float4 y;
    y.x = sx * so; y.y = sy * so; y.z = sz * so; y.w = sw * so;
    const size_t o = (size_t)grow * ND + e4 * 4;
    if (layer == 0) {
        *(float4*)(accbuf + o) = y;
    } else if (layer == 1) {
        float4 a = *(const float4*)(accbuf + o);
        a.x += y.x; a.y += y.y; a.z += y.z; a.w += y.w;
        *(float4*)(accbuf + o) = a;
    } else {
        float4 a = *(const float4*)(accbuf + o);
        a.x = (a.x + y.x) * 0.25f; a.y = (a.y + y.y) * 0.25f;
        a.z = (a.z + y.z) * 0.25f; a.w = (a.w + y.w) * 0.25f;
        *(float4*)(out + o) = a;
    }
    if (layer != 2) {
        const float fn = (grow < NU) ? dsu[grow] : dsi[grow - NU];
        TB[e4 * 4 + 0][rl] = f2bf(y.x * fn);
        TB[e4 * 4 + 1][rl] = f2bf(y.y * fn);
        TB[e4 * 4 + 2][rl] = f2bf(y.z * fn);
        TB[e4 * 4 + 3][rl] = f2bf(y.w * fn);
        __syncthreads();
        if (t < 128) {
            const int e = t >> 1, h = t & 1;
            u16* dstF; int nb;
            if (bx < 256)      { dstF = BuFn; nb = bx * 16; }
            else if (bx < 512) { dstF = BiFn; nb = bx * 16 - NU; }
            else               { dstF = BiFn; nb = (NI - NU) + (bx - 512) * 16; }
            const int q0 = (nb >> 3) & 7;
            const size_t cb = (size_t)(((nb >> 9) << 3) + ((nb >> 6) & 7)) * 4096;
            uint4 v = *(const uint4*)&TB[e][h * 8];
            *(uint4*)&dstF[cb + (size_t)(e >> 4) * 1024
                           + (size_t)(q0 + h) * 128 + (e & 15) * 8] = v;
        }
    }
}

extern "C" void kernel_launch(void* const* d_in, const int* in_sizes, int n_in,
                              void* d_out, int out_size, void* d_ws, size_t ws_size,
                              hipStream_t stream) {
    (void)in_sizes; (void)n_in; (void)out_size; (void)ws_size;
    const float* x    = (const float*)d_in[0];
    const int*   edge = (const int*)d_in[1];
    float* out = (float*)d_out;

    char* ws = (char*)d_ws;
    size_t off = 0;
    u64* Apk  = (u64*)(ws + off); off += (size_t)NU * (NI / 64) * 8;   // 4 MiB
    u64* ATpk = (u64*)(ws + off); off += (size_t)NI * (NU / 64) * 8;   // 4 MiB
    float* dsu = (float*)(ws + off); off += (size_t)NU * 4;
    float* dsi = (float*)(ws + off); off += (size_t)NI * 4;
    u16* BuF0 = (u16*)(ws + off); off += (size_t)ND * NU * 2;
    u16* BuF1 = (u16*)(ws + off); off += (size_t)ND * NU * 2;
    u16* BiF0 = (u16*)(ws + off); off += (size_t)ND * NI * 2;
    u16* BiF1 = (u16*)(ws + off); off += (size_t)ND * NI * 2;
    float* acc  = (float*)(ws + off); off += (size_t)NTOT * ND * 4;
    float* Ptop = (float*)(ws + off); off += (size_t)NI * CT * 64 * 4; // 16 MiB
    float* Pbot = (float*)(ws + off); off += (size_t)NU * CB * 64 * 4; // 16 MiB

    k_pack2<<<512, 256, 0, stream>>>(edge, Apk, ATpk);
    k_scale0<<<NTOT / 64, 256, 0, stream>>>(x, Apk, ATpk, dsu, dsi, BuF0, BiF0);

    k_gemm<<<2048, 256, 0, stream>>>(Apk, ATpk, BuF0, BiF0, Ptop, Pbot);
    k_reduce<<<768, 256, 0, stream>>>(Ptop, Pbot, dsu, dsi, acc, BuF1, BiF1, out, 0);
    k_gemm<<<2048, 256, 0, stream>>>(Apk, ATpk, BuF1, BiF1, Ptop, Pbot);
    k_reduce<<<768, 256, 0, stream>>>(Ptop, Pbot, dsu, dsi, acc, BuF0, BiF0, out, 1);
    k_gemm<<<2048, 256, 0, stream>>>(Apk, ATpk, BuF0, BiF0, Ptop, Pbot);
    k_reduce<<<768, 256, 0, stream>>>(Ptop, Pbot, dsu, dsi, acc,
                                      (u16*)nullptr, (u16*)nullptr, out, 2);
}